// Round 3
// baseline (5279.578 us; speedup 1.0000x reference)
//
#include <hip/hip_runtime.h>

#define N_NODES 50000
#define N_EDGES 800000
#define F 128
#define K2 256

typedef unsigned short u16;
typedef __bf16 bf16x8 __attribute__((ext_vector_type(8)));
typedef float f32x4 __attribute__((ext_vector_type(4)));

__device__ inline u16 f2bf(float f) {
  union { float f; unsigned u; } v; v.f = f;
  unsigned r = v.u + 0x7fffu + ((v.u >> 16) & 1u);
  return (u16)(r >> 16);
}

__device__ inline int clampi(int v) {
  v = v < 0 ? 0 : v;
  return v >= N_NODES ? N_NODES - 1 : v;
}

// load 8 contiguous fp32 and round-convert to a bf16x8 MFMA fragment
__device__ inline bf16x8 pack8(const float* __restrict__ p) {
  float4 a = *(const float4*)p;
  float4 b = *(const float4*)(p + 4);
  bf16x8 r;
  r[0] = (__bf16)a.x; r[1] = (__bf16)a.y; r[2] = (__bf16)a.z; r[3] = (__bf16)a.w;
  r[4] = (__bf16)b.x; r[5] = (__bf16)b.y; r[6] = (__bf16)b.z; r[7] = (__bf16)b.w;
  return r;
}

// ---------- zero d_out (graph-capture-safe, no memset) ----------
__global__ void zero_out_kernel(float* __restrict__ out) {
  int stride = gridDim.x * blockDim.x;
  int n = (N_NODES * F) / 4;
  f32x4 z = {};
  for (int i = blockIdx.x * blockDim.x + threadIdx.x; i < n; i += stride)
    ((f32x4*)out)[i] = z;
}

// ---------- transpose weights to bf16, n-major ----------
// wt[n*128+k]  = W[k][n]; w1t[n*256+k] = ew_W1[k][n]
__global__ void prep_weights_kernel(const float* __restrict__ W, const float* __restrict__ W1,
                                    u16* __restrict__ wt, u16* __restrict__ w1t) {
  int t = blockIdx.x * blockDim.x + threadIdx.x;
  if (t < 128 * 128) {
    int k = t >> 7, n = t & 127;
    wt[n * 128 + k] = f2bf(W[k * 128 + n]);
  } else {
    int t2 = t - 128 * 128;
    int k = t2 >> 7, n = t2 & 127;
    w1t[n * 256 + k] = f2bf(W1[k * 128 + n]);
  }
}

// ---------- x_t = x @ W + b  (bf16 MFMA, bf16 out to ws) ----------
#define WTP 136  // 272B row stride: 16B aligned, 4-bank shift/row
__global__ __launch_bounds__(256) void xform_kernel(
    const float* __restrict__ x, const u16* __restrict__ wt,
    const float* __restrict__ bias, u16* __restrict__ xt)
{
  __shared__ u16 wl[128 * WTP];
  for (int c = threadIdx.x; c < 128 * 16; c += 256) {
    int nrow = c >> 4, ko = (c & 15) * 8;
    *(bf16x8*)&wl[nrow * WTP + ko] = *(const bf16x8*)(wt + nrow * 128 + ko);
  }
  __syncthreads();
  int w = threadIdx.x >> 6, l = threadIdx.x & 63;
  int r2 = l & 15, q = l >> 4;
  int rowbase = blockIdx.x * 128 + w * 32;
  float bv[8];
#pragma unroll
  for (int nf = 0; nf < 8; nf++) bv[nf] = bias[r2 + 16 * nf];
  int ra0 = rowbase + r2;       if (ra0 >= N_NODES) ra0 = N_NODES - 1;
  int ra1 = rowbase + 16 + r2;  if (ra1 >= N_NODES) ra1 = N_NODES - 1;
  const float* pa0 = x + ra0 * F + q * 8;
  const float* pa1 = x + ra1 * F + q * 8;
  f32x4 acc0[8] = {}, acc1[8] = {};
#pragma unroll
  for (int k = 0; k < 4; k++) {
    bf16x8 a0 = pack8(pa0 + 32 * k);
    bf16x8 a1 = pack8(pa1 + 32 * k);
#pragma unroll
    for (int nf = 0; nf < 8; nf++) {
      bf16x8 b = *(const bf16x8*)&wl[(16 * nf + r2) * WTP + q * 8 + 32 * k];
      acc0[nf] = __builtin_amdgcn_mfma_f32_16x16x32_bf16(a0, b, acc0[nf], 0, 0, 0);
      acc1[nf] = __builtin_amdgcn_mfma_f32_16x16x32_bf16(a1, b, acc1[nf], 0, 0, 0);
    }
  }
#pragma unroll
  for (int nf = 0; nf < 8; nf++) {
#pragma unroll
    for (int r = 0; r < 4; r++) {
      int row0 = rowbase + 4 * q + r;
      int row1 = row0 + 16;
      int c = r2 + 16 * nf;
      if (row0 < N_NODES) xt[row0 * F + c] = f2bf(acc0[nf][r] + bv[nf]);
      if (row1 < N_NODES) xt[row1 * F + c] = f2bf(acc1[nf][r] + bv[nf]);
    }
  }
}

// ---------- edge kernel: MLP gate + gated scatter ----------
// LDS exactly 64KB: [128 rows][32 slots of 8 elems], slot XOR-swizzled by (row&7)
#define TILE_EDGES 128
__global__ __launch_bounds__(256) void edge_kernel(
    const float* __restrict__ x, const u16* __restrict__ xt,
    const u16* __restrict__ w1t,
    const float* __restrict__ b1, const float* __restrict__ w2f,
    const float* __restrict__ b2, const int* __restrict__ ei,
    float* __restrict__ out)
{
  __shared__ u16 w1l[128 * 256];
  for (int c = threadIdx.x; c < 128 * 32; c += 256) {
    int nrow = c >> 5, slot = c & 31;
    *(bf16x8*)&w1l[nrow * 256 + ((slot ^ (nrow & 7)) << 3)] =
        *(const bf16x8*)(w1t + nrow * 256 + (slot << 3));
  }
  __syncthreads();
  int w = threadIdx.x >> 6, l = threadIdx.x & 63;
  int r2 = l & 15, q = l >> 4;
  int sw = r2 & 7;
  float b1v[8], w2v[8];
#pragma unroll
  for (int nf = 0; nf < 8; nf++) {
    b1v[nf] = b1[r2 + 16 * nf];
    w2v[nf] = w2f[r2 + 16 * nf];
  }
  float bias2 = b2[0];
  const int ntiles = N_EDGES / TILE_EDGES;
  for (int tile = blockIdx.x; tile < ntiles; tile += gridDim.x) {
    int ebase = tile * TILE_EDGES + w * 32;
    int s0 = clampi(ei[ebase + r2]);
    int d0 = clampi(ei[N_EDGES + ebase + r2]);
    int s1 = clampi(ei[ebase + 16 + r2]);
    int d1 = clampi(ei[N_EDGES + ebase + 16 + r2]);
    const float* ps0 = x + s0 * F + q * 8;
    const float* pd0 = x + d0 * F + q * 8;
    const float* ps1 = x + s1 * F + q * 8;
    const float* pd1 = x + d1 * F + q * 8;
    f32x4 acc0[8] = {}, acc1[8] = {};
#pragma unroll
    for (int k = 0; k < 8; k++) {
      const float* pa0 = (k < 4) ? (ps0 + 32 * k) : (pd0 + 32 * (k - 4));
      const float* pa1 = (k < 4) ? (ps1 + 32 * k) : (pd1 + 32 * (k - 4));
      bf16x8 a0 = pack8(pa0);
      bf16x8 a1 = pack8(pa1);
#pragma unroll
      for (int nf = 0; nf < 8; nf++) {
        bf16x8 b = *(const bf16x8*)&w1l[(16 * nf + r2) * 256 + (((q + 4 * k) ^ sw) << 3)];
        acc0[nf] = __builtin_amdgcn_mfma_f32_16x16x32_bf16(a0, b, acc0[nf], 0, 0, 0);
        acc1[nf] = __builtin_amdgcn_mfma_f32_16x16x32_bf16(a1, b, acc1[nf], 0, 0, 0);
      }
    }
    // relu(h+b1)·w2, reduce across the 16 lanes of each quarter
    float t0[4], t1[4];
#pragma unroll
    for (int r = 0; r < 4; r++) {
      float sa = 0.f, sb = 0.f;
#pragma unroll
      for (int nf = 0; nf < 8; nf++) {
        float h0 = acc0[nf][r] + b1v[nf]; h0 = h0 > 0.f ? h0 : 0.f;
        float h1 = acc1[nf][r] + b1v[nf]; h1 = h1 > 0.f ? h1 : 0.f;
        sa += h0 * w2v[nf]; sb += h1 * w2v[nf];
      }
#pragma unroll
      for (int d = 1; d < 16; d <<= 1) {
        sa += __shfl_xor(sa, d);
        sb += __shfl_xor(sb, d);
      }
      t0[r] = sa; t1[r] = sb;
    }
    // scatter: lane -> (edge, column half) such that the gate is already lane-local
    int rr = r2 & 3;
    int e = 4 * q + rr + ((r2 & 8) ? 16 : 0);
    int ch = (r2 & 4) ? 64 : 0;
    float z0 = rr == 0 ? t0[0] : rr == 1 ? t0[1] : rr == 2 ? t0[2] : t0[3];
    float z1 = rr == 0 ? t1[0] : rr == 1 ? t1[1] : rr == 2 ? t1[2] : t1[3];
    float z = (r2 & 8) ? z1 : z0;
    float ew = 1.0f / (1.0f + __expf(-(z + bias2)));
    int se = clampi(ei[tile * TILE_EDGES + w * 32 + e]);
    int de = clampi(ei[N_EDGES + tile * TILE_EDGES + w * 32 + e]);
    const u16* xr = xt + se * F + ch;
    float* op = out + de * F + ch;
#pragma unroll
    for (int i = 0; i < 8; i++) {
      bf16x8 v = *(const bf16x8*)(xr + 8 * i);
#pragma unroll
      for (int j = 0; j < 8; j++)
        atomicAdd(op + 8 * i + j, ew * (float)v[j]);
    }
  }
}

extern "C" void kernel_launch(void* const* d_in, const int* in_sizes, int n_in,
                              void* d_out, int out_size, void* d_ws, size_t ws_size,
                              hipStream_t stream) {
  const float* x  = (const float*)d_in[0];
  const int* ei   = (const int*)d_in[1];   // int64 in reference -> int32 in harness
  const float* W  = (const float*)d_in[2];
  const float* b  = (const float*)d_in[3];
  const float* W1 = (const float*)d_in[4];
  const float* b1 = (const float*)d_in[5];
  const float* W2 = (const float*)d_in[6];
  const float* b2 = (const float*)d_in[7];
  float* out = (float*)d_out;

  char* ws = (char*)d_ws;
  u16* xt  = (u16*)ws;                   // 12,800,000 B (x_t in bf16)
  u16* wt  = (u16*)(ws + 12800000);      //     32,768 B
  u16* w1t = (u16*)(ws + 12832768);      //     65,536 B   (total ~12.9 MB)

  zero_out_kernel<<<1024, 256, 0, stream>>>(out);
  prep_weights_kernel<<<192, 256, 0, stream>>>(W, W1, wt, w1t);
  xform_kernel<<<391, 256, 0, stream>>>(x, wt, b, xt);
  edge_kernel<<<512, 256, 0, stream>>>(x, xt, w1t, b1, W2, b2, ei, out);
}

// Round 4
// 451.249 us; speedup vs baseline: 11.6999x; 11.6999x over previous
//
#include <hip/hip_runtime.h>

#define N_NODES 50000
#define N_EDGES 800000
#define F 128
#define K2 256

typedef unsigned short u16;
typedef __bf16 bf16x8 __attribute__((ext_vector_type(8)));
typedef float f32x4 __attribute__((ext_vector_type(4)));

__device__ inline u16 f2bf(float f) {
  union { float f; unsigned u; } v; v.f = f;
  unsigned r = v.u + 0x7fffu + ((v.u >> 16) & 1u);
  return (u16)(r >> 16);
}

__device__ inline int clampi(int v) {
  v = v < 0 ? 0 : v;
  return v >= N_NODES ? N_NODES - 1 : v;
}

__device__ inline bf16x8 pack8(const float* __restrict__ p) {
  float4 a = *(const float4*)p;
  float4 b = *(const float4*)(p + 4);
  bf16x8 r;
  r[0] = (__bf16)a.x; r[1] = (__bf16)a.y; r[2] = (__bf16)a.z; r[3] = (__bf16)a.w;
  r[4] = (__bf16)b.x; r[5] = (__bf16)b.y; r[6] = (__bf16)b.z; r[7] = (__bf16)b.w;
  return r;
}

// ---------- zero degree counters ----------
__global__ void zero_deg_kernel(int* __restrict__ deg) {
  int i = blockIdx.x * blockDim.x + threadIdx.x;
  if (i < N_NODES) deg[i] = 0;
}

// ---------- histogram of dst ----------
__global__ void hist_kernel(const int* __restrict__ ei, int* __restrict__ deg) {
  int e = blockIdx.x * blockDim.x + threadIdx.x;
  if (e < N_EDGES) atomicAdd(&deg[clampi(ei[N_EDGES + e])], 1);
}

// ---------- single-block exclusive scan over 50000 degrees ----------
__global__ __launch_bounds__(1024) void scan_kernel(const int* __restrict__ deg,
                                                    int* __restrict__ offsets,
                                                    int* __restrict__ cursor) {
  __shared__ int wsum[16];
  __shared__ int sbase;
  int t = threadIdx.x, lane = t & 63, wid = t >> 6;
  if (t == 0) sbase = 0;
  __syncthreads();
  for (int base = 0; base < N_NODES; base += 1024) {
    int i = base + t;
    int v = (i < N_NODES) ? deg[i] : 0;
    int s = v;
#pragma unroll
    for (int d = 1; d < 64; d <<= 1) {
      int u = __shfl_up(s, d);
      if (lane >= d) s += u;
    }
    if (lane == 63) wsum[wid] = s;
    __syncthreads();
    if (wid == 0 && lane < 16) {
      int ws = wsum[lane];
#pragma unroll
      for (int d = 1; d < 16; d <<= 1) {
        int u = __shfl_up(ws, d);
        if (lane >= d) ws += u;
      }
      wsum[lane] = ws;  // inclusive per-wave totals
    }
    __syncthreads();
    int wprev = (wid == 0) ? 0 : wsum[wid - 1];
    int excl = sbase + wprev + s - v;
    if (i < N_NODES) { offsets[i] = excl; cursor[i] = excl; }
    __syncthreads();
    if (t == 1023) sbase = sbase + wprev + s;  // += chunk total
    __syncthreads();
  }
  if (t == 0) offsets[N_NODES] = sbase;
}

// ---------- reorder: perm[sorted_slot] = original edge id ----------
__global__ void reorder_kernel(const int* __restrict__ ei, int* __restrict__ cursor,
                               int* __restrict__ perm) {
  int e = blockIdx.x * blockDim.x + threadIdx.x;
  if (e < N_EDGES) {
    int d = clampi(ei[N_EDGES + e]);
    int p = atomicAdd(&cursor[d], 1);
    perm[p] = e;
  }
}

// ---------- transpose weights to bf16, n-major ----------
__global__ void prep_weights_kernel(const float* __restrict__ W, const float* __restrict__ W1,
                                    u16* __restrict__ wt, u16* __restrict__ w1t) {
  int t = blockIdx.x * blockDim.x + threadIdx.x;
  if (t < 128 * 128) {
    int k = t >> 7, n = t & 127;
    wt[n * 128 + k] = f2bf(W[k * 128 + n]);
  } else {
    int t2 = t - 128 * 128;
    int k = t2 >> 7, n = t2 & 127;
    w1t[n * 256 + k] = f2bf(W1[k * 128 + n]);
  }
}

// ---------- x_t = x @ W + b  (bf16 MFMA, bf16 out to ws) ----------
#define WTP 136
__global__ __launch_bounds__(256) void xform_kernel(
    const float* __restrict__ x, const u16* __restrict__ wt,
    const float* __restrict__ bias, u16* __restrict__ xt)
{
  __shared__ u16 wl[128 * WTP];
  for (int c = threadIdx.x; c < 128 * 16; c += 256) {
    int nrow = c >> 4, ko = (c & 15) * 8;
    *(bf16x8*)&wl[nrow * WTP + ko] = *(const bf16x8*)(wt + nrow * 128 + ko);
  }
  __syncthreads();
  int w = threadIdx.x >> 6, l = threadIdx.x & 63;
  int r2 = l & 15, q = l >> 4;
  int rowbase = blockIdx.x * 128 + w * 32;
  float bv[8];
#pragma unroll
  for (int nf = 0; nf < 8; nf++) bv[nf] = bias[r2 + 16 * nf];
  int ra0 = rowbase + r2;       if (ra0 >= N_NODES) ra0 = N_NODES - 1;
  int ra1 = rowbase + 16 + r2;  if (ra1 >= N_NODES) ra1 = N_NODES - 1;
  const float* pa0 = x + ra0 * F + q * 8;
  const float* pa1 = x + ra1 * F + q * 8;
  f32x4 acc0[8] = {}, acc1[8] = {};
#pragma unroll
  for (int k = 0; k < 4; k++) {
    bf16x8 a0 = pack8(pa0 + 32 * k);
    bf16x8 a1 = pack8(pa1 + 32 * k);
#pragma unroll
    for (int nf = 0; nf < 8; nf++) {
      bf16x8 b = *(const bf16x8*)&wl[(16 * nf + r2) * WTP + q * 8 + 32 * k];
      acc0[nf] = __builtin_amdgcn_mfma_f32_16x16x32_bf16(a0, b, acc0[nf], 0, 0, 0);
      acc1[nf] = __builtin_amdgcn_mfma_f32_16x16x32_bf16(a1, b, acc1[nf], 0, 0, 0);
    }
  }
#pragma unroll
  for (int nf = 0; nf < 8; nf++) {
#pragma unroll
    for (int r = 0; r < 4; r++) {
      int row0 = rowbase + 4 * q + r;
      int row1 = row0 + 16;
      int c = r2 + 16 * nf;
      if (row0 < N_NODES) xt[row0 * F + c] = f2bf(acc0[nf][r] + bv[nf]);
      if (row1 < N_NODES) xt[row1 * F + c] = f2bf(acc1[nf][r] + bv[nf]);
    }
  }
}

// ---------- gate kernel: edge MLP -> ew[e] (no scatter) ----------
#define TILE_EDGES 128
__global__ __launch_bounds__(256) void gate_kernel(
    const float* __restrict__ x, const u16* __restrict__ w1t,
    const float* __restrict__ b1, const float* __restrict__ w2f,
    const float* __restrict__ b2, const int* __restrict__ ei,
    float* __restrict__ ew)
{
  __shared__ u16 w1l[128 * 256];
  for (int c = threadIdx.x; c < 128 * 32; c += 256) {
    int nrow = c >> 5, slot = c & 31;
    *(bf16x8*)&w1l[nrow * 256 + ((slot ^ (nrow & 7)) << 3)] =
        *(const bf16x8*)(w1t + nrow * 256 + (slot << 3));
  }
  __syncthreads();
  int w = threadIdx.x >> 6, l = threadIdx.x & 63;
  int r2 = l & 15, q = l >> 4;
  int sw = r2 & 7;
  float b1v[8], w2v[8];
#pragma unroll
  for (int nf = 0; nf < 8; nf++) {
    b1v[nf] = b1[r2 + 16 * nf];
    w2v[nf] = w2f[r2 + 16 * nf];
  }
  float bias2 = b2[0];
  const int ntiles = N_EDGES / TILE_EDGES;
  for (int tile = blockIdx.x; tile < ntiles; tile += gridDim.x) {
    int ebase = tile * TILE_EDGES + w * 32;
    int s0 = clampi(ei[ebase + r2]);
    int d0 = clampi(ei[N_EDGES + ebase + r2]);
    int s1 = clampi(ei[ebase + 16 + r2]);
    int d1 = clampi(ei[N_EDGES + ebase + 16 + r2]);
    const float* ps0 = x + s0 * F + q * 8;
    const float* pd0 = x + d0 * F + q * 8;
    const float* ps1 = x + s1 * F + q * 8;
    const float* pd1 = x + d1 * F + q * 8;
    f32x4 acc0[8] = {}, acc1[8] = {};
#pragma unroll
    for (int k = 0; k < 8; k++) {
      const float* pa0 = (k < 4) ? (ps0 + 32 * k) : (pd0 + 32 * (k - 4));
      const float* pa1 = (k < 4) ? (ps1 + 32 * k) : (pd1 + 32 * (k - 4));
      bf16x8 a0 = pack8(pa0);
      bf16x8 a1 = pack8(pa1);
#pragma unroll
      for (int nf = 0; nf < 8; nf++) {
        bf16x8 b = *(const bf16x8*)&w1l[(16 * nf + r2) * 256 + (((q + 4 * k) ^ sw) << 3)];
        acc0[nf] = __builtin_amdgcn_mfma_f32_16x16x32_bf16(a0, b, acc0[nf], 0, 0, 0);
        acc1[nf] = __builtin_amdgcn_mfma_f32_16x16x32_bf16(a1, b, acc1[nf], 0, 0, 0);
      }
    }
    float t0[4], t1[4];
#pragma unroll
    for (int r = 0; r < 4; r++) {
      float sa = 0.f, sb = 0.f;
#pragma unroll
      for (int nf = 0; nf < 8; nf++) {
        float h0 = acc0[nf][r] + b1v[nf]; h0 = h0 > 0.f ? h0 : 0.f;
        float h1 = acc1[nf][r] + b1v[nf]; h1 = h1 > 0.f ? h1 : 0.f;
        sa += h0 * w2v[nf]; sb += h1 * w2v[nf];
      }
#pragma unroll
      for (int d = 1; d < 16; d <<= 1) {
        sa += __shfl_xor(sa, d);
        sb += __shfl_xor(sb, d);
      }
      t0[r] = sa; t1[r] = sb;
    }
    // one gate per edge; lanes with (r2&4)==0 each own one of the 32 edges
    int rr = r2 & 3;
    int e = 4 * q + rr + ((r2 & 8) ? 16 : 0);
    float z0 = rr == 0 ? t0[0] : rr == 1 ? t0[1] : rr == 2 ? t0[2] : t0[3];
    float z1 = rr == 0 ? t1[0] : rr == 1 ? t1[1] : rr == 2 ? t1[2] : t1[3];
    float z = (r2 & 8) ? z1 : z0;
    if ((r2 & 4) == 0)
      ew[tile * TILE_EDGES + w * 32 + e] = 1.0f / (1.0f + __expf(-(z + bias2)));
  }
}

// ---------- aggregation: one wave per dst node, no atomics ----------
__global__ __launch_bounds__(256) void aggregate_kernel(
    const u16* __restrict__ xt, const int* __restrict__ offsets,
    const int* __restrict__ perm, const int* __restrict__ ei,
    const float* __restrict__ ew, float* __restrict__ out)
{
  int n = (blockIdx.x * blockDim.x + threadIdx.x) >> 6;
  int lane = threadIdx.x & 63;
  if (n >= N_NODES) return;
  int p = offsets[n], end = offsets[n + 1];
  float a0 = 0.f, a1 = 0.f;
  for (; p + 1 < end; p += 2) {
    int e0 = perm[p], e1 = perm[p + 1];
    int s0 = clampi(ei[e0]), s1 = clampi(ei[e1]);
    float w0 = ew[e0], w1 = ew[e1];
    unsigned v0 = *(const unsigned*)(xt + s0 * F + 2 * lane);
    unsigned v1 = *(const unsigned*)(xt + s1 * F + 2 * lane);
    a0 += w0 * __uint_as_float(v0 << 16) + w1 * __uint_as_float(v1 << 16);
    a1 += w0 * __uint_as_float(v0 & 0xffff0000u) + w1 * __uint_as_float(v1 & 0xffff0000u);
  }
  if (p < end) {
    int e0 = perm[p];
    int s0 = clampi(ei[e0]);
    float w0 = ew[e0];
    unsigned v0 = *(const unsigned*)(xt + s0 * F + 2 * lane);
    a0 += w0 * __uint_as_float(v0 << 16);
    a1 += w0 * __uint_as_float(v0 & 0xffff0000u);
  }
  out[n * F + 2 * lane] = a0;
  out[n * F + 2 * lane + 1] = a1;
}

extern "C" void kernel_launch(void* const* d_in, const int* in_sizes, int n_in,
                              void* d_out, int out_size, void* d_ws, size_t ws_size,
                              hipStream_t stream) {
  const float* x  = (const float*)d_in[0];
  const int* ei   = (const int*)d_in[1];   // int64 in reference -> int32 in harness
  const float* W  = (const float*)d_in[2];
  const float* b  = (const float*)d_in[3];
  const float* W1 = (const float*)d_in[4];
  const float* b1 = (const float*)d_in[5];
  const float* W2 = (const float*)d_in[6];
  const float* b2 = (const float*)d_in[7];
  float* out = (float*)d_out;

  char* ws = (char*)d_ws;
  u16* xt      = (u16*)ws;                    // 12,800,000 B
  u16* wt      = (u16*)(ws + 12800000);       //     32,768 B
  u16* w1t     = (u16*)(ws + 12832768);       //     65,536 B
  int* offsets = (int*)(ws + 12898304);       //    200,004 B
  int* deg     = (int*)(ws + 13098308);       //    200,000 B
  int* cursor  = (int*)(ws + 13298308);       //    200,000 B
  int* perm    = (int*)(ws + 13498308);       //  3,200,000 B
  float* ewbuf = (float*)(ws + 16698308);     //  3,200,000 B  (total ~19.9 MB)

  zero_deg_kernel<<<(N_NODES + 255) / 256, 256, 0, stream>>>(deg);
  prep_weights_kernel<<<192, 256, 0, stream>>>(W, W1, wt, w1t);
  hist_kernel<<<(N_EDGES + 255) / 256, 256, 0, stream>>>(ei, deg);
  scan_kernel<<<1, 1024, 0, stream>>>(deg, offsets, cursor);
  reorder_kernel<<<(N_EDGES + 255) / 256, 256, 0, stream>>>(ei, cursor, perm);
  xform_kernel<<<391, 256, 0, stream>>>(x, wt, b, xt);
  gate_kernel<<<512, 256, 0, stream>>>(x, w1t, b1, W2, b2, ei, ewbuf);
  aggregate_kernel<<<(N_NODES * 64 + 255) / 256, 256, 0, stream>>>(xt, offsets, perm, ei, ewbuf, out);
}